// Round 1
// baseline (182.058 us; speedup 1.0000x reference)
//
#include <hip/hip_runtime.h>
#include <math.h>

#define NB 4
#define NT 128
#define NS 512
#define NH 256

__device__ __forceinline__ float fast_tanh(float x) {
    // tanh(x) = 1 - 2/(exp(2x)+1); safe at +/-inf, ~1e-7 rel err with __expf
    float e = __expf(2.0f * x);
    return 1.0f - 2.0f / (e + 1.0f);
}

// pq[r, o] = sum_h q[r,h] * Ws[o,h]   (one block per row r, thread = o)
__global__ __launch_bounds__(256) void proj_pq_kernel(
    const float* __restrict__ q, const float* __restrict__ Ws,
    float* __restrict__ pq)
{
    __shared__ float x[NH];
    const int r = blockIdx.x, tid = threadIdx.x;
    x[tid] = q[r * NH + tid];
    __syncthreads();
    const float4* w4 = reinterpret_cast<const float4*>(Ws + (size_t)tid * NH);
    const float4* x4 = reinterpret_cast<const float4*>(x);
    float acc = 0.f;
#pragma unroll 8
    for (int i = 0; i < NH / 4; ++i) {
        float4 wv = w4[i], xv = x4[i];
        acc = fmaf(wv.x, xv.x, acc);
        acc = fmaf(wv.y, xv.y, acc);
        acc = fmaf(wv.z, xv.z, acc);
        acc = fmaf(wv.w, xv.w, acc);
    }
    pq[r * NH + tid] = acc;
}

// peT[b, o, s] = sum_h enc[b,s,h] * Wh[o,h]   (one block per (b,s) row, thread = o)
// stored transposed (B,H,S) so the score loop reads contiguously along s
__global__ __launch_bounds__(256) void proj_peT_kernel(
    const float* __restrict__ enc, const float* __restrict__ Wh,
    float* __restrict__ peT)
{
    __shared__ float x[NH];
    const int r = blockIdx.x, tid = threadIdx.x;
    const int b = r / NS, s = r % NS;
    x[tid] = enc[(size_t)r * NH + tid];
    __syncthreads();
    const float4* w4 = reinterpret_cast<const float4*>(Wh + (size_t)tid * NH);
    const float4* x4 = reinterpret_cast<const float4*>(x);
    float acc = 0.f;
#pragma unroll 8
    for (int i = 0; i < NH / 4; ++i) {
        float4 wv = w4[i], xv = x4[i];
        acc = fmaf(wv.x, xv.x, acc);
        acc = fmaf(wv.y, xv.y, acc);
        acc = fmaf(wv.z, xv.z, acc);
        acc = fmaf(wv.w, xv.w, acc);
    }
    peT[(size_t)b * NH * NS + (size_t)tid * NS + s] = acc;
}

// One block per (b,t): scores + masked softmax + context + output projection
__global__ __launch_bounds__(256) void attn_fused_kernel(
    const float* __restrict__ q, const float* __restrict__ enc,
    const int* __restrict__ lens, const float* __restrict__ v,
    const float* __restrict__ Wout, const float* __restrict__ pq,
    const float* __restrict__ peT, float* __restrict__ out)
{
    __shared__ float pq_sh[NH];
    __shared__ float v_sh[NH];
    __shared__ float q_sh[NH];
    __shared__ float alpha[NS];
    __shared__ float c_sh[NH];
    __shared__ float redA[4];
    __shared__ float redB[4];

    const int bt = blockIdx.x;
    const int b = bt / NT;
    const int tid = threadIdx.x;

    pq_sh[tid] = pq[bt * NH + tid];
    v_sh[tid] = v[tid];
    q_sh[tid] = q[bt * NH + tid];
    __syncthreads();

    const int len = lens[b];
    const float* peTb = peT + (size_t)b * NH * NS;

    // --- scores: thread owns s0 = tid, s1 = tid + 256 ---
    const int s0 = tid, s1 = tid + 256;
    float e0 = 0.f, e1 = 0.f;
#pragma unroll 4
    for (int h = 0; h < NH; ++h) {
        const float ph = pq_sh[h];
        const float vh = v_sh[h];
        const float* row = peTb + (size_t)h * NS;
        e0 = fmaf(vh, fast_tanh(ph + row[s0]), e0);
        e1 = fmaf(vh, fast_tanh(ph + row[s1]), e1);
    }
    if (s0 >= len) e0 = -INFINITY;
    if (s1 >= len) e1 = -INFINITY;

    // --- block max over 512 scores ---
    float m = fmaxf(e0, e1);
#pragma unroll
    for (int off = 32; off; off >>= 1) m = fmaxf(m, __shfl_xor(m, off));
    const int wave = tid >> 6;
    if ((tid & 63) == 0) redA[wave] = m;
    __syncthreads();
    m = fmaxf(fmaxf(redA[0], redA[1]), fmaxf(redA[2], redA[3]));

    // --- exp + block sum ---
    const float p0 = __expf(e0 - m);  // exp(-inf) = 0 for masked lanes
    const float p1 = __expf(e1 - m);
    float sum = p0 + p1;
#pragma unroll
    for (int off = 32; off; off >>= 1) sum += __shfl_xor(sum, off);
    if ((tid & 63) == 0) redB[wave] = sum;
    __syncthreads();
    sum = redB[0] + redB[1] + redB[2] + redB[3];
    const float rsum = 1.0f / sum;

    alpha[s0] = p0 * rsum;
    alpha[s1] = p1 * rsum;
    __syncthreads();

    // --- context: thread owns h = tid, coalesced enc reads ---
    const float* encb = enc + (size_t)b * NS * NH;
    float acc = 0.f;
#pragma unroll 4
    for (int s = 0; s < len; ++s) {
        acc = fmaf(alpha[s], encb[(size_t)s * NH + tid], acc);
    }
    c_sh[tid] = acc;
    __syncthreads();

    // --- output projection: thread owns o = tid ---
    const float4* wrow = reinterpret_cast<const float4*>(Wout + (size_t)tid * 2 * NH);
    const float4* q4 = reinterpret_cast<const float4*>(q_sh);
    const float4* c4 = reinterpret_cast<const float4*>(c_sh);
    float acc2 = 0.f;
#pragma unroll 8
    for (int i = 0; i < NH / 4; ++i) {
        float4 wv = wrow[i], xv = q4[i];
        acc2 = fmaf(wv.x, xv.x, acc2);
        acc2 = fmaf(wv.y, xv.y, acc2);
        acc2 = fmaf(wv.z, xv.z, acc2);
        acc2 = fmaf(wv.w, xv.w, acc2);
    }
#pragma unroll 8
    for (int i = 0; i < NH / 4; ++i) {
        float4 wv = wrow[NH / 4 + i], xv = c4[i];
        acc2 = fmaf(wv.x, xv.x, acc2);
        acc2 = fmaf(wv.y, xv.y, acc2);
        acc2 = fmaf(wv.z, xv.z, acc2);
        acc2 = fmaf(wv.w, xv.w, acc2);
    }
    out[bt * NH + tid] = fast_tanh(acc2);
}

extern "C" void kernel_launch(void* const* d_in, const int* in_sizes, int n_in,
                              void* d_out, int out_size, void* d_ws, size_t ws_size,
                              hipStream_t stream) {
    const float* q    = (const float*)d_in[0];  // (B,T,H)
    const float* enc  = (const float*)d_in[1];  // (B,S,H)
    const int*   lens = (const int*)d_in[2];    // (B,)
    const float* Ws   = (const float*)d_in[3];  // (H,H)
    const float* Wh   = (const float*)d_in[4];  // (H,H)
    const float* v    = (const float*)d_in[5];  // (H,)
    const float* Wout = (const float*)d_in[6];  // (H,2H)
    float* out = (float*)d_out;                 // (B,T,H)

    float* pq  = (float*)d_ws;                  // B*T*H floats
    float* peT = pq + (size_t)NB * NT * NH;     // B*H*S floats

    proj_pq_kernel<<<NB * NT, 256, 0, stream>>>(q, Ws, pq);
    proj_peT_kernel<<<NB * NS, 256, 0, stream>>>(enc, Wh, peT);
    attn_fused_kernel<<<NB * NT, 256, 0, stream>>>(q, enc, lens, v, Wout, pq, peT, out);
}

// Round 2
// 115.321 us; speedup vs baseline: 1.5787x; 1.5787x over previous
//
#include <hip/hip_runtime.h>
#include <math.h>

#define NB 4
#define NT 128
#define NS 512
#define NH 256

__device__ __forceinline__ float fast_tanh(float x) {
    // tanh(x) = 1 - 2/(exp(2x)+1); safe at +/-inf, ~1e-7 rel err with __expf
    float e = __expf(2.0f * x);
    return 1.0f - 2.0f / (e + 1.0f);
}

__device__ __forceinline__ float dot4(float4 a, float4 b, float acc) {
    acc = fmaf(a.x, b.x, acc);
    acc = fmaf(a.y, b.y, acc);
    acc = fmaf(a.z, b.z, acc);
    acc = fmaf(a.w, b.w, acc);
    return acc;
}

// peT[b, o, s] = sum_h enc[b,s,h] * Wh[o,h], stored transposed (B,H,S).
// 4 encoder rows per block: amortize Wh reads 4x, 4 independent acc chains,
// contiguous float4 write of the transposed output.
__global__ __launch_bounds__(256) void proj_peT_kernel(
    const float* __restrict__ enc, const float* __restrict__ Wh,
    float* __restrict__ peT)
{
    __shared__ float x[4][NH];
    const int r0 = blockIdx.x * 4;            // first of 4 rows (NS%4==0 so same b)
    const int b = r0 >> 9;                    // / NS
    const int s0 = r0 & (NS - 1);
    const int tid = threadIdx.x;
#pragma unroll
    for (int i = 0; i < 4; ++i)
        x[i][tid] = enc[(size_t)(r0 + i) * NH + tid];
    __syncthreads();

    const float4* w4 = reinterpret_cast<const float4*>(Wh + (size_t)tid * NH);
    const float4* x0 = reinterpret_cast<const float4*>(x[0]);
    const float4* x1 = reinterpret_cast<const float4*>(x[1]);
    const float4* x2 = reinterpret_cast<const float4*>(x[2]);
    const float4* x3 = reinterpret_cast<const float4*>(x[3]);
    float a0 = 0.f, a1 = 0.f, a2 = 0.f, a3 = 0.f;
#pragma unroll 8
    for (int i = 0; i < NH / 4; ++i) {
        float4 wv = w4[i];
        a0 = dot4(wv, x0[i], a0);
        a1 = dot4(wv, x1[i], a1);
        a2 = dot4(wv, x2[i], a2);
        a3 = dot4(wv, x3[i], a3);
    }
    float4 r = make_float4(a0, a1, a2, a3);
    *reinterpret_cast<float4*>(peT + (size_t)b * NH * NS + (size_t)tid * NS + s0) = r;
}

// One block of 1024 threads per (b,t): pq projection + scores + masked softmax
// + context + output projection, every phase split 2-4 ways for occupancy.
__global__ __launch_bounds__(1024, 8) void attn_fused_kernel(
    const float* __restrict__ q, const float* __restrict__ enc,
    const int* __restrict__ lens, const float* __restrict__ Ws,
    const float* __restrict__ v, const float* __restrict__ Wout,
    const float* __restrict__ peT, float* __restrict__ out)
{
    __shared__ float pq_sh[NH];
    __shared__ float v_sh[NH];
    __shared__ float q_sh[NH];
    __shared__ float c_sh[NH];
    __shared__ float alpha[NS];
    __shared__ float part_sh[1024];
    __shared__ float redA[16];
    __shared__ float redB[16];

    const int bt = blockIdx.x;
    const int b = bt >> 7;                    // / NT
    const int tid = threadIdx.x;
    const int lane = tid & 63;
    const int wave = tid >> 6;

    if (tid < NH) q_sh[tid] = q[bt * NH + tid];
    else if (tid < 2 * NH) v_sh[tid - NH] = v[tid - NH];
    __syncthreads();

    // --- pq[o] = sum_h q[h]*Ws[o,h], split K 4 ways: thread = (o, part) ---
    {
        const int o = tid & (NH - 1);
        const int part = tid >> 8;            // 0..3, 64 elems each
        const float4* w4 = reinterpret_cast<const float4*>(Ws + (size_t)o * NH + part * 64);
        const float4* x4 = reinterpret_cast<const float4*>(q_sh + part * 64);
        float acc = 0.f;
#pragma unroll
        for (int i = 0; i < 16; ++i) acc = dot4(w4[i], x4[i], acc);
        part_sh[tid] = acc;
    }
    __syncthreads();
    if (tid < NH)
        pq_sh[tid] = part_sh[tid] + part_sh[NH + tid] + part_sh[2 * NH + tid] + part_sh[3 * NH + tid];
    __syncthreads();

    const int len = lens[b];
    const float* peTb = peT + (size_t)b * NH * NS;

    // --- scores: thread = (s, h-half); 128 h-iters each ---
    {
        const int s = tid & (NS - 1);
        const int half = tid >> 9;            // 0..1
        const int h0 = half * (NH / 2);
        float e = 0.f;
#pragma unroll 4
        for (int h = h0; h < h0 + NH / 2; ++h) {
            e = fmaf(v_sh[h], fast_tanh(pq_sh[h] + peTb[(size_t)h * NS + s]), e);
        }
        part_sh[tid] = e;
    }
    __syncthreads();

    const int s = tid & (NS - 1);
    float e = -INFINITY;
    if (tid < NS) {
        e = part_sh[s] + part_sh[NS + s];
        if (s >= len) e = -INFINITY;
    }

    // --- block max over 512 scores (threads >= 512 hold -inf) ---
    float m = e;
#pragma unroll
    for (int off = 32; off; off >>= 1) m = fmaxf(m, __shfl_xor(m, off));
    if (lane == 0) redA[wave] = m;
    __syncthreads();
    m = redA[0];
#pragma unroll
    for (int w = 1; w < 16; ++w) m = fmaxf(m, redA[w]);

    // --- exp + block sum ---
    const float p = (tid < NS) ? __expf(e - m) : 0.f;   // exp(-inf)=0 masked
    float sum = p;
#pragma unroll
    for (int off = 32; off; off >>= 1) sum += __shfl_xor(sum, off);
    if (lane == 0) redB[wave] = sum;
    __syncthreads();
    sum = redB[0];
#pragma unroll
    for (int w = 1; w < 16; ++w) sum += redB[w];
    const float rsum = 1.0f / sum;
    if (tid < NS) alpha[s] = p * rsum;
    __syncthreads();

    // --- context: thread = (h, s-quarter); 128 s-iters each, coalesced enc ---
    {
        const int h = tid & (NH - 1);
        const int quar = tid >> 8;            // 0..3
        const float* encb = enc + (size_t)b * NS * NH;
        float acc = 0.f;
#pragma unroll 4
        for (int si = quar * (NS / 4); si < (quar + 1) * (NS / 4); ++si) {
            acc = fmaf(alpha[si], encb[(size_t)si * NH + h], acc);
        }
        part_sh[tid] = acc;
    }
    __syncthreads();
    if (tid < NH)
        c_sh[tid] = part_sh[tid] + part_sh[NH + tid] + part_sh[2 * NH + tid] + part_sh[3 * NH + tid];
    __syncthreads();

    // --- output projection: thread = (o, col-quarter of 128); cat=[q,c] ---
    {
        const int o = tid & (NH - 1);
        const int part = tid >> 8;            // 0..3
        const float* xsrc = (part < 2) ? (q_sh + part * 128) : (c_sh + (part - 2) * 128);
        const float4* w4 = reinterpret_cast<const float4*>(Wout + (size_t)o * 2 * NH + part * 128);
        const float4* x4 = reinterpret_cast<const float4*>(xsrc);
        float acc = 0.f;
#pragma unroll
        for (int i = 0; i < 32; ++i) acc = dot4(w4[i], x4[i], acc);
        part_sh[tid] = acc;
    }
    __syncthreads();
    if (tid < NH) {
        float r = part_sh[tid] + part_sh[NH + tid] + part_sh[2 * NH + tid] + part_sh[3 * NH + tid];
        out[bt * NH + tid] = fast_tanh(r);
    }
}

extern "C" void kernel_launch(void* const* d_in, const int* in_sizes, int n_in,
                              void* d_out, int out_size, void* d_ws, size_t ws_size,
                              hipStream_t stream) {
    const float* q    = (const float*)d_in[0];  // (B,T,H)
    const float* enc  = (const float*)d_in[1];  // (B,S,H)
    const int*   lens = (const int*)d_in[2];    // (B,)
    const float* Ws   = (const float*)d_in[3];  // (H,H)
    const float* Wh   = (const float*)d_in[4];  // (H,H)
    const float* v    = (const float*)d_in[5];  // (H,)
    const float* Wout = (const float*)d_in[6];  // (H,2H)
    float* out = (float*)d_out;                 // (B,T,H)

    float* peT = (float*)d_ws;                  // B*H*S floats

    proj_peT_kernel<<<NB * NS / 4, 256, 0, stream>>>(enc, Wh, peT);
    attn_fused_kernel<<<NB * NT, 1024, 0, stream>>>(q, enc, lens, Ws, v, Wout, peT, out);
}

// Round 3
// 81.389 us; speedup vs baseline: 2.2369x; 1.4169x over previous
//
#include <hip/hip_runtime.h>
#include <math.h>

#define NB 4
#define NT 128
#define NS 512
#define NH 256

__device__ __forceinline__ float fast_tanh(float x) {
    // tanh(x) = 1 - 2/(exp(2x)+1); safe at +/-inf
    float e = __expf(2.0f * x);
    return 1.0f - 2.0f / (e + 1.0f);
}

__device__ __forceinline__ float dot4(float4 a, float4 b, float acc) {
    acc = fmaf(a.x, b.x, acc);
    acc = fmaf(a.y, b.y, acc);
    acc = fmaf(a.z, b.z, acc);
    acc = fmaf(a.w, b.w, acc);
    return acc;
}

// ---------------------------------------------------------------------------
// K1: projections. rows [0, NB*NS) -> pe' = 2*(enc row . Wh[o,:])
//                  rows [NB*NS, ..) -> pq' = 2*(q row . Ws[o,:])
// 8 rows/block, 512 threads: o = tid&255 (output col), rh = tid>>8 (row half).
// X rows are block/wave-uniform -> scalar loads; W rows per-thread (L2-served).
// Block 0 also writes w[h] = -2*v[h].
// ---------------------------------------------------------------------------
__global__ __launch_bounds__(512) void k1_proj(
    const float* __restrict__ enc, const float* __restrict__ q,
    const float* __restrict__ Wh, const float* __restrict__ Ws,
    const float* __restrict__ v,
    float* __restrict__ pe, float* __restrict__ pq, float* __restrict__ w)
{
    const int r0 = blockIdx.x * 8;
    const bool is_pe = (r0 < NB * NS);
    const float* __restrict__ W = is_pe ? Wh : Ws;
    const float* __restrict__ X = is_pe ? enc : q;
    float* __restrict__ dst = is_pe ? pe : pq;
    const int xr0 = is_pe ? r0 : (r0 - NB * NS);

    const int o  = threadIdx.x & 255;
    const int rh = __builtin_amdgcn_readfirstlane(threadIdx.x >> 8);
    const int rb = xr0 + rh * 4;

    const float4* __restrict__ W4 = reinterpret_cast<const float4*>(W + (size_t)o * NH);
    const float4* __restrict__ x0 = reinterpret_cast<const float4*>(X + (size_t)(rb + 0) * NH);
    const float4* __restrict__ x1 = reinterpret_cast<const float4*>(X + (size_t)(rb + 1) * NH);
    const float4* __restrict__ x2 = reinterpret_cast<const float4*>(X + (size_t)(rb + 2) * NH);
    const float4* __restrict__ x3 = reinterpret_cast<const float4*>(X + (size_t)(rb + 3) * NH);

    float a0 = 0.f, a1 = 0.f, a2 = 0.f, a3 = 0.f;
#pragma unroll 8
    for (int i = 0; i < NH / 4; ++i) {
        float4 wv = W4[i];
        a0 = dot4(wv, x0[i], a0);
        a1 = dot4(wv, x1[i], a1);
        a2 = dot4(wv, x2[i], a2);
        a3 = dot4(wv, x3[i], a3);
    }
    dst[(size_t)(rb + 0) * NH + o] = a0 * 2.0f;
    dst[(size_t)(rb + 1) * NH + o] = a1 * 2.0f;
    dst[(size_t)(rb + 2) * NH + o] = a2 * 2.0f;
    dst[(size_t)(rb + 3) * NH + o] = a3 * 2.0f;

    if (blockIdx.x == 0 && threadIdx.x < NH) w[threadIdx.x] = -2.0f * v[threadIdx.x];
}

// ---------------------------------------------------------------------------
// K2: scores (up to softmax-invariant constant):
//   e'[t,s] = sum_h w[h] / (exp(pe'[s,h] + pq'[t,h]) + 1)
// Block = (b, 16 t, 64 s); 512 threads: s = tid&63, tg = tid>>6 -> t = {tg, tg+8}.
// pe-slice (64 rows x 256 h) staged in LDS, XOR-swizzled for conflict-free
// ds_read_b128. pq/w read with wave-uniform addresses (scalar loads).
// ---------------------------------------------------------------------------
__global__ __launch_bounds__(512) void k2_score(
    const float* __restrict__ pe, const float* __restrict__ pq,
    const float* __restrict__ w, float* __restrict__ e)
{
    __shared__ float4 pesh[64 * 64];  // 64 s-rows x 64 float4 (h), swizzled

    const int sx = blockIdx.x;        // s-tile (8)
    const int ty = blockIdx.y;        // t-tile (8)
    const int b  = blockIdx.z;
    const int tid = threadIdx.x;

    // stage pe slice: 8 threads/row, strided j for conflict-free swizzled writes
    {
        const int row = tid >> 3;
        const int jl  = tid & 7;
        const float4* src = reinterpret_cast<const float4*>(
            pe + (size_t)(b * NS + sx * 64 + row) * NH);
        const int rsw = row & 7;
#pragma unroll
        for (int k = 0; k < 8; ++k) {
            const int j = jl + 8 * k;
            pesh[row * 64 + (j ^ rsw)] = src[j];
        }
    }
    __syncthreads();

    const int s  = tid & 63;
    const int tg = __builtin_amdgcn_readfirstlane(tid >> 6);
    const int t0 = ty * 16 + tg;
    const int t1 = t0 + 8;

    const float4* __restrict__ pqA = reinterpret_cast<const float4*>(pq + (size_t)(b * NT + t0) * NH);
    const float4* __restrict__ pqB = reinterpret_cast<const float4*>(pq + (size_t)(b * NT + t1) * NH);
    const float4* __restrict__ w4  = reinterpret_cast<const float4*>(w);

    float acc0 = 0.f, acc1 = 0.f;
    const int ssw = s & 7;
#pragma unroll 4
    for (int h4 = 0; h4 < 64; ++h4) {
        const float4 pv = pesh[s * 64 + (h4 ^ ssw)];
        const float4 a0 = pqA[h4];
        const float4 a1 = pqB[h4];
        const float4 wv = w4[h4];

        acc0 = fmaf(wv.x, __builtin_amdgcn_rcpf(__expf(pv.x + a0.x) + 1.0f), acc0);
        acc0 = fmaf(wv.y, __builtin_amdgcn_rcpf(__expf(pv.y + a0.y) + 1.0f), acc0);
        acc0 = fmaf(wv.z, __builtin_amdgcn_rcpf(__expf(pv.z + a0.z) + 1.0f), acc0);
        acc0 = fmaf(wv.w, __builtin_amdgcn_rcpf(__expf(pv.w + a0.w) + 1.0f), acc0);

        acc1 = fmaf(wv.x, __builtin_amdgcn_rcpf(__expf(pv.x + a1.x) + 1.0f), acc1);
        acc1 = fmaf(wv.y, __builtin_amdgcn_rcpf(__expf(pv.y + a1.y) + 1.0f), acc1);
        acc1 = fmaf(wv.z, __builtin_amdgcn_rcpf(__expf(pv.z + a1.z) + 1.0f), acc1);
        acc1 = fmaf(wv.w, __builtin_amdgcn_rcpf(__expf(pv.w + a1.w) + 1.0f), acc1);
    }
    e[(size_t)(b * NT + t0) * NS + sx * 64 + s] = acc0;
    e[(size_t)(b * NT + t1) * NS + sx * 64 + s] = acc1;
}

// ---------------------------------------------------------------------------
// K3: masked softmax + context, block = (b, 8 t, 64 h), 256 threads.
// e rows staged+masked in LDS; per-wave softmax (2 rows/wave); context with
// coalesced enc reads (all waves share the same slice -> L1).
// ---------------------------------------------------------------------------
__global__ __launch_bounds__(256) void k3_ctx(
    const float* __restrict__ e, const float* __restrict__ enc,
    const int* __restrict__ lens, float* __restrict__ c)
{
    __shared__ float es[8][NS];
    __shared__ float rs[8];

    const int ht = blockIdx.x;        // h-tile (4)
    const int tt = blockIdx.y;        // t-tile (16)
    const int b  = blockIdx.z;
    const int tid = threadIdx.x;
    const int len = lens[b];
    const int t_base = tt * 8;

    // load + mask e rows: 32 threads/row, float4 cols
    {
        const int r  = tid >> 5;
        const int c0 = tid & 31;
        const float4* src = reinterpret_cast<const float4*>(
            e + (size_t)(b * NT + t_base + r) * NS);
#pragma unroll
        for (int k = 0; k < 4; ++k) {
            const int f4 = c0 + k * 32;
            float4 vv = src[f4];
            const int sbase = f4 * 4;
            if (sbase + 0 >= len) vv.x = -INFINITY;
            if (sbase + 1 >= len) vv.y = -INFINITY;
            if (sbase + 2 >= len) vv.z = -INFINITY;
            if (sbase + 3 >= len) vv.w = -INFINITY;
            reinterpret_cast<float4*>(&es[r][0])[f4] = vv;
        }
    }
    __syncthreads();

    // softmax: wave wv handles rows 2wv, 2wv+1 (unnormalized; keep 1/sum)
    const int wv = tid >> 6, lane = tid & 63;
    for (int rr = 0; rr < 2; ++rr) {
        const int r = wv * 2 + rr;
        float vals[8];
        float m = -INFINITY;
#pragma unroll
        for (int k = 0; k < 8; ++k) { vals[k] = es[r][lane + 64 * k]; m = fmaxf(m, vals[k]); }
#pragma unroll
        for (int off = 32; off; off >>= 1) m = fmaxf(m, __shfl_xor(m, off));
        float sum = 0.f;
#pragma unroll
        for (int k = 0; k < 8; ++k) {
            const float p = __expf(vals[k] - m);   // exp(-inf)=0 for masked
            sum += p;
            es[r][lane + 64 * k] = p;
        }
#pragma unroll
        for (int off = 32; off; off >>= 1) sum += __shfl_xor(sum, off);
        if (lane == 0) rs[r] = 1.0f / sum;
    }
    __syncthreads();

    // context: thread = (hl 0..63, tg 0..3 -> t = 2tg, 2tg+1)
    const int hl = tid & 63, tg = tid >> 6;
    const int ta = tg * 2, tb = ta + 1;
    const float* ep = enc + (size_t)b * NS * NH + ht * 64 + hl;
    const float4* e4a = reinterpret_cast<const float4*>(&es[ta][0]);
    const float4* e4b = reinterpret_cast<const float4*>(&es[tb][0]);
    float a0 = 0.f, a1 = 0.f;
#pragma unroll 2
    for (int s4 = 0; s4 < NS / 4; ++s4) {
        const float4 w0 = e4a[s4];
        const float4 w1 = e4b[s4];
        const float x0 = ep[(size_t)(s4 * 4 + 0) * NH];
        const float x1 = ep[(size_t)(s4 * 4 + 1) * NH];
        const float x2 = ep[(size_t)(s4 * 4 + 2) * NH];
        const float x3 = ep[(size_t)(s4 * 4 + 3) * NH];
        a0 = fmaf(w0.x, x0, a0); a0 = fmaf(w0.y, x1, a0);
        a0 = fmaf(w0.z, x2, a0); a0 = fmaf(w0.w, x3, a0);
        a1 = fmaf(w1.x, x0, a1); a1 = fmaf(w1.y, x1, a1);
        a1 = fmaf(w1.z, x2, a1); a1 = fmaf(w1.w, x3, a1);
    }
    c[(size_t)(b * NT + t_base + ta) * NH + ht * 64 + hl] = a0 * rs[ta];
    c[(size_t)(b * NT + t_base + tb) * NH + ht * 64 + hl] = a1 * rs[tb];
}

// ---------------------------------------------------------------------------
// K4: out[bt,o] = tanh(cat[bt,:] . Wout[o,:]), cat = [q | c], K = 512.
// Block = (8 bt-rows, 64 o-cols), 256 threads: o = tid&63, tg = tid>>6 ->
// t = {2tg, 2tg+1}. cat staged once (16KB); Wout in 4 chunks of 32KB,
// XOR-swizzled rows for conflict-free b128 reads.
// ---------------------------------------------------------------------------
__global__ __launch_bounds__(256) void k4_out(
    const float* __restrict__ qin, const float* __restrict__ cin,
    const float* __restrict__ Wout, float* __restrict__ out)
{
    __shared__ float4 wsh[64 * 32];   // 64 o-rows x 32 f4 chunk, swizzled
    __shared__ float4 csh[8 * 128];   // 8 rows x 128 f4 = [q|c]

    const int ot  = blockIdx.x;       // o-tile (4)
    const int btt = blockIdx.y;       // bt-tile (64)
    const int tid = threadIdx.x;
    const int bt0 = btt * 8;

    // stage cat
    {
        const int r  = tid >> 5;
        const int f0 = tid & 31;
        const float4* q4 = reinterpret_cast<const float4*>(qin + (size_t)(bt0 + r) * NH);
        const float4* c4 = reinterpret_cast<const float4*>(cin + (size_t)(bt0 + r) * NH);
#pragma unroll
        for (int k = 0; k < 4; ++k) {
            const int f4 = f0 + k * 32;
            csh[r * 128 + f4] = (f4 < 64) ? q4[f4] : c4[f4 - 64];
        }
    }

    const int o  = tid & 63;
    const int tg = tid >> 6;
    const int ta = tg * 2, tb = ta + 1;
    const int osw = o & 7;
    float acc0 = 0.f, acc1 = 0.f;

    for (int ch = 0; ch < 4; ++ch) {
        __syncthreads();
        // stage Wout chunk: 4 threads/row, 8 f4 each (strided)
        {
            const int r  = tid >> 2;
            const int jl = tid & 3;
            const float4* src = reinterpret_cast<const float4*>(
                Wout + (size_t)(ot * 64 + r) * (2 * NH)) + ch * 32;
            const int rsw = r & 7;
#pragma unroll
            for (int k = 0; k < 8; ++k) {
                const int j = jl + 4 * k;
                wsh[r * 32 + (j ^ rsw)] = src[j];
            }
        }
        __syncthreads();

#pragma unroll 8
        for (int j = 0; j < 32; ++j) {
            const float4 wv = wsh[o * 32 + (j ^ osw)];
            const float4 xa = csh[ta * 128 + ch * 32 + j];
            const float4 xb = csh[tb * 128 + ch * 32 + j];
            acc0 = dot4(wv, xa, acc0);
            acc1 = dot4(wv, xb, acc1);
        }
    }

    out[(size_t)(bt0 + ta) * NH + ot * 64 + o] = fast_tanh(acc0);
    out[(size_t)(bt0 + tb) * NH + ot * 64 + o] = fast_tanh(acc1);
}

extern "C" void kernel_launch(void* const* d_in, const int* in_sizes, int n_in,
                              void* d_out, int out_size, void* d_ws, size_t ws_size,
                              hipStream_t stream) {
    const float* q    = (const float*)d_in[0];  // (B,T,H)
    const float* enc  = (const float*)d_in[1];  // (B,S,H)
    const int*   lens = (const int*)d_in[2];    // (B,)
    const float* Ws   = (const float*)d_in[3];  // (H,H)
    const float* Wh   = (const float*)d_in[4];  // (H,H)
    const float* v    = (const float*)d_in[5];  // (H,)
    const float* Wout = (const float*)d_in[6];  // (H,2H)
    float* out = (float*)d_out;                 // (B,T,H)

    float* pe = (float*)d_ws;                    // NB*NS*NH
    float* pq = pe + (size_t)NB * NS * NH;       // NB*NT*NH
    float* w  = pq + (size_t)NB * NT * NH;       // NH
    float* e  = w + NH;                          // NB*NT*NS
    float* c  = pe;                              // reuse pe region (dead after K2)

    k1_proj<<<NB * (NS + NT) / 8, 512, 0, stream>>>(enc, q, Wh, Ws, v, pe, pq, w);
    k2_score<<<dim3(NS / 64, NT / 16, NB), 512, 0, stream>>>(pe, pq, w, e);
    k3_ctx<<<dim3(NH / 64, NT / 8, NB), 256, 0, stream>>>(e, enc, lens, c);
    k4_out<<<dim3(NH / 64, NB * NT / 8), 256, 0, stream>>>(q, c, Wout, out);
}

// Round 4
// 69.966 us; speedup vs baseline: 2.6021x; 1.1633x over previous
//
#include <hip/hip_runtime.h>
#include <math.h>

#define NB 4
#define NT 128
#define NS 512
#define NH 256

__device__ __forceinline__ float fast_tanh(float x) {
    // tanh(x) = 1 - 2/(exp(2x)+1); safe at +/-inf
    float e = __expf(2.0f * x);
    return 1.0f - 2.0f / (e + 1.0f);
}

__device__ __forceinline__ float dot4(float4 a, float4 b, float acc) {
    acc = fmaf(a.x, b.x, acc);
    acc = fmaf(a.y, b.y, acc);
    acc = fmaf(a.z, b.z, acc);
    acc = fmaf(a.w, b.w, acc);
    return acc;
}

// ---------------------------------------------------------------------------
// K1: projections, scaled by 2: pe'[r,o] = 2*(enc[r,:].Wh[o,:]),
//     pq'[r,o] = 2*(q[r,:].Ws[o,:]); also w[h] = -2*v[h].
// Template: lanes = o (weight rows), W-tile (64 o x 256 h = 64KB) staged in
// LDS XOR-swizzled; X rows are wave-uniform -> s_load; writes coalesced.
// Block 512 thr = 8 waves x 4 m-rows = 32 rows; grid 80 m-tiles x 4 o-tiles.
// ---------------------------------------------------------------------------
__global__ __launch_bounds__(512) void k1_proj(
    const float* __restrict__ enc, const float* __restrict__ q,
    const float* __restrict__ Wh, const float* __restrict__ Ws,
    const float* __restrict__ v,
    float* __restrict__ pe, float* __restrict__ pq, float* __restrict__ w)
{
    __shared__ float4 wsh[64 * 64];   // 64 o-rows x 64 f4 (256 h), swizzled

    const int bx = blockIdx.x;
    const int mt = bx >> 2;           // 0..79 (32-row tiles)
    const int ot = bx & 3;            // 0..3  (64-o tiles)
    const bool is_pe = (mt < 64);     // enc rows 2048 = 64 tiles
    const float* __restrict__ X = is_pe ? enc : q;
    const float* __restrict__ W = is_pe ? Wh : Ws;
    float* __restrict__ dst = is_pe ? pe : pq;
    const int r0 = (is_pe ? mt : (mt - 64)) * 32;
    const int tid = threadIdx.x;

    // stage W tile: rows ot*64..+64, 8 thr/row x 8 f4, XOR-swizzled low-3
    {
        const int row = tid >> 3, jl = tid & 7;
        const float4* src = reinterpret_cast<const float4*>(W + (size_t)(ot * 64 + row) * NH);
        const int rsw = row & 7;
#pragma unroll
        for (int kk = 0; kk < 8; ++kk) {
            const int j = jl + 8 * kk;
            wsh[row * 64 + (j ^ rsw)] = src[j];
        }
    }
    __syncthreads();

    const int o  = tid & 63;
    const int wv = __builtin_amdgcn_readfirstlane(tid >> 6);  // 0..7
    const int m0 = r0 + wv * 4;

    const float4* __restrict__ x0 = reinterpret_cast<const float4*>(X + (size_t)(m0 + 0) * NH);
    const float4* __restrict__ x1 = reinterpret_cast<const float4*>(X + (size_t)(m0 + 1) * NH);
    const float4* __restrict__ x2 = reinterpret_cast<const float4*>(X + (size_t)(m0 + 2) * NH);
    const float4* __restrict__ x3 = reinterpret_cast<const float4*>(X + (size_t)(m0 + 3) * NH);

    float a0 = 0.f, a1 = 0.f, a2 = 0.f, a3 = 0.f;
    const int osw = o & 7;
#pragma unroll 8
    for (int k4 = 0; k4 < 64; ++k4) {
        const float4 wq = wsh[o * 64 + (k4 ^ osw)];
        a0 = dot4(wq, x0[k4], a0);
        a1 = dot4(wq, x1[k4], a1);
        a2 = dot4(wq, x2[k4], a2);
        a3 = dot4(wq, x3[k4], a3);
    }
    const int oc = ot * 64 + o;
    dst[(size_t)(m0 + 0) * NH + oc] = a0 * 2.0f;
    dst[(size_t)(m0 + 1) * NH + oc] = a1 * 2.0f;
    dst[(size_t)(m0 + 2) * NH + oc] = a2 * 2.0f;
    dst[(size_t)(m0 + 3) * NH + oc] = a3 * 2.0f;

    if (bx == 0 && tid < NH) w[tid] = -2.0f * v[tid];
}

// ---------------------------------------------------------------------------
// K2: scores (softmax-shift-invariant form):
//   e'[t,s] = sum_h w[h] / (exp(pe'[s,h] + pq'[t,h]) + 1)
// Block = (b, 8 t, 64 s), 512 thr: s = tid&63, tg = tid>>6 -> 1 t each.
// pe slice (64 s x 256 h) LDS-staged XOR-swizzled; pq/w wave-uniform s_loads.
// Grid 512 blocks -> 4 waves/SIMD to saturate the trans pipe.
// ---------------------------------------------------------------------------
__global__ __launch_bounds__(512) void k2_score(
    const float* __restrict__ pe, const float* __restrict__ pq,
    const float* __restrict__ w, float* __restrict__ e)
{
    __shared__ float4 pesh[64 * 64];  // 64 s-rows x 64 f4, swizzled

    const int sx = blockIdx.x;        // s-tile (8)
    const int ty = blockIdx.y;        // t-tile (16)
    const int b  = blockIdx.z;
    const int tid = threadIdx.x;

    {
        const int row = tid >> 3, jl = tid & 7;
        const float4* src = reinterpret_cast<const float4*>(
            pe + (size_t)(b * NS + sx * 64 + row) * NH);
        const int rsw = row & 7;
#pragma unroll
        for (int kk = 0; kk < 8; ++kk) {
            const int j = jl + 8 * kk;
            pesh[row * 64 + (j ^ rsw)] = src[j];
        }
    }
    __syncthreads();

    const int s  = tid & 63;
    const int tg = __builtin_amdgcn_readfirstlane(tid >> 6);
    const int t  = ty * 8 + tg;

    const float4* __restrict__ pqA = reinterpret_cast<const float4*>(pq + (size_t)(b * NT + t) * NH);
    const float4* __restrict__ w4  = reinterpret_cast<const float4*>(w);

    float acc = 0.f;
    const int ssw = s & 7;
#pragma unroll 4
    for (int h4 = 0; h4 < 64; ++h4) {
        const float4 pv = pesh[s * 64 + (h4 ^ ssw)];
        const float4 aq = pqA[h4];
        const float4 wv = w4[h4];
        acc = fmaf(wv.x, __builtin_amdgcn_rcpf(__expf(pv.x + aq.x) + 1.0f), acc);
        acc = fmaf(wv.y, __builtin_amdgcn_rcpf(__expf(pv.y + aq.y) + 1.0f), acc);
        acc = fmaf(wv.z, __builtin_amdgcn_rcpf(__expf(pv.z + aq.z) + 1.0f), acc);
        acc = fmaf(wv.w, __builtin_amdgcn_rcpf(__expf(pv.w + aq.w) + 1.0f), acc);
    }
    e[(size_t)(b * NT + t) * NS + sx * 64 + s] = acc;
}

// ---------------------------------------------------------------------------
// K3: masked softmax + context. Block = 4 independent waves, wave = 1 t-row,
// lanes = 64 h-cols (coalesced enc). Softmax fully in-register (f4 loads +
// shfl); P-row parked in LDS for uniform broadcast during context.
// Grid (4 ht, 32 tt, 4 b) = 512 blocks.
// ---------------------------------------------------------------------------
__global__ __launch_bounds__(256) void k3_ctx(
    const float* __restrict__ e, const float* __restrict__ enc,
    const int* __restrict__ lens, float* __restrict__ c)
{
    __shared__ float ps[4][NS];

    const int ht = blockIdx.x;
    const int tt = blockIdx.y;
    const int b  = blockIdx.z;
    const int tid  = threadIdx.x;
    const int lane = tid & 63;
    const int wv   = __builtin_amdgcn_readfirstlane(tid >> 6);
    const int t    = tt * 4 + wv;
    const int len  = lens[b];

    // --- in-register masked softmax of row t (8 vals/lane) ---
    const float4* erow = reinterpret_cast<const float4*>(e + (size_t)(b * NT + t) * NS);
    float4 va = erow[lane];
    float4 vb = erow[lane + 64];
    const int c0 = 4 * lane;          // cols of va
    const int c1 = 256 + 4 * lane;    // cols of vb
    if (c0 + 0 >= len) va.x = -INFINITY;
    if (c0 + 1 >= len) va.y = -INFINITY;
    if (c0 + 2 >= len) va.z = -INFINITY;
    if (c0 + 3 >= len) va.w = -INFINITY;
    if (c1 + 0 >= len) vb.x = -INFINITY;
    if (c1 + 1 >= len) vb.y = -INFINITY;
    if (c1 + 2 >= len) vb.z = -INFINITY;
    if (c1 + 3 >= len) vb.w = -INFINITY;

    float m = fmaxf(fmaxf(fmaxf(va.x, va.y), fmaxf(va.z, va.w)),
                    fmaxf(fmaxf(vb.x, vb.y), fmaxf(vb.z, vb.w)));
#pragma unroll
    for (int off = 32; off; off >>= 1) m = fmaxf(m, __shfl_xor(m, off));

    va.x = __expf(va.x - m); va.y = __expf(va.y - m);
    va.z = __expf(va.z - m); va.w = __expf(va.w - m);
    vb.x = __expf(vb.x - m); vb.y = __expf(vb.y - m);
    vb.z = __expf(vb.z - m); vb.w = __expf(vb.w - m);

    float sum = va.x + va.y + va.z + va.w + vb.x + vb.y + vb.z + vb.w;
#pragma unroll
    for (int off = 32; off; off >>= 1) sum += __shfl_xor(sum, off);
    const float rsum = 1.0f / sum;

    float4* ps4w = reinterpret_cast<float4*>(&ps[wv][0]);
    ps4w[lane] = va;
    ps4w[lane + 64] = vb;
    __syncthreads();   // belt-and-braces LDS write->read ordering

    // --- context: lane = h-col, wave = its own t-row; 4 partial chains ---
    const float* ep = enc + (size_t)b * NS * NH + ht * 64 + lane;
    const float4* p4 = reinterpret_cast<const float4*>(&ps[wv][0]);
    float acc0 = 0.f, acc1 = 0.f, acc2 = 0.f, acc3 = 0.f;
#pragma unroll 2
    for (int s4 = 0; s4 < 32; ++s4) {
        {
            const float4 pw = p4[s4];
            const float* eb = ep + (size_t)(4 * s4) * NH;
            acc0 = fmaf(pw.x, eb[0],      acc0);
            acc0 = fmaf(pw.y, eb[NH],     acc0);
            acc0 = fmaf(pw.z, eb[2 * NH], acc0);
            acc0 = fmaf(pw.w, eb[3 * NH], acc0);
        }
        {
            const float4 pw = p4[s4 + 32];
            const float* eb = ep + (size_t)(4 * (s4 + 32)) * NH;
            acc1 = fmaf(pw.x, eb[0],      acc1);
            acc1 = fmaf(pw.y, eb[NH],     acc1);
            acc1 = fmaf(pw.z, eb[2 * NH], acc1);
            acc1 = fmaf(pw.w, eb[3 * NH], acc1);
        }
        {
            const float4 pw = p4[s4 + 64];
            const float* eb = ep + (size_t)(4 * (s4 + 64)) * NH;
            acc2 = fmaf(pw.x, eb[0],      acc2);
            acc2 = fmaf(pw.y, eb[NH],     acc2);
            acc2 = fmaf(pw.z, eb[2 * NH], acc2);
            acc2 = fmaf(pw.w, eb[3 * NH], acc2);
        }
        {
            const float4 pw = p4[s4 + 96];
            const float* eb = ep + (size_t)(4 * (s4 + 96)) * NH;
            acc3 = fmaf(pw.x, eb[0],      acc3);
            acc3 = fmaf(pw.y, eb[NH],     acc3);
            acc3 = fmaf(pw.z, eb[2 * NH], acc3);
            acc3 = fmaf(pw.w, eb[3 * NH], acc3);
        }
    }
    c[(size_t)(b * NT + t) * NH + ht * 64 + lane] =
        (acc0 + acc1 + acc2 + acc3) * rsum;
}

// ---------------------------------------------------------------------------
// K4: out[bt,o] = tanh(cat[bt,:].Wout[o,:]), cat = [q|c]. Same template as
// K1: lanes = o, Wout half-tiles (64 o x 256 k = 64KB) staged swizzled;
// cat rows wave-uniform s_loads (half 0 = q, half 1 = c). 8 waves = 8 bt rows.
// Grid 64 bt-tiles x 4 o-tiles = 256 blocks.
// ---------------------------------------------------------------------------
__global__ __launch_bounds__(512) void k4_out(
    const float* __restrict__ qin, const float* __restrict__ cin,
    const float* __restrict__ Wout, float* __restrict__ out)
{
    __shared__ float4 wsh[64 * 64];

    const int ot  = blockIdx.x & 3;
    const int btt = blockIdx.x >> 2;  // 0..63
    const int tid = threadIdx.x;
    const int o   = tid & 63;
    const int wv  = __builtin_amdgcn_readfirstlane(tid >> 6);
    const int bt  = btt * 8 + wv;
    const int osw = o & 7;

    float acc = 0.f;
#pragma unroll
    for (int half = 0; half < 2; ++half) {
        __syncthreads();
        {
            const int row = tid >> 3, jl = tid & 7;
            const float4* src = reinterpret_cast<const float4*>(
                Wout + (size_t)(ot * 64 + row) * (2 * NH) + half * NH);
            const int rsw = row & 7;
#pragma unroll
            for (int kk = 0; kk < 8; ++kk) {
                const int j = jl + 8 * kk;
                wsh[row * 64 + (j ^ rsw)] = src[j];
            }
        }
        __syncthreads();

        const float4* __restrict__ xr = reinterpret_cast<const float4*>(
            (half ? cin : qin) + (size_t)bt * NH);
#pragma unroll 8
        for (int k4 = 0; k4 < 64; ++k4) {
            acc = dot4(wsh[o * 64 + (k4 ^ osw)], xr[k4], acc);
        }
    }
    out[(size_t)bt * NH + ot * 64 + o] = fast_tanh(acc);
}

extern "C" void kernel_launch(void* const* d_in, const int* in_sizes, int n_in,
                              void* d_out, int out_size, void* d_ws, size_t ws_size,
                              hipStream_t stream) {
    const float* q    = (const float*)d_in[0];  // (B,T,H)
    const float* enc  = (const float*)d_in[1];  // (B,S,H)
    const int*   lens = (const int*)d_in[2];    // (B,)
    const float* Ws   = (const float*)d_in[3];  // (H,H)
    const float* Wh   = (const float*)d_in[4];  // (H,H)
    const float* v    = (const float*)d_in[5];  // (H,)
    const float* Wout = (const float*)d_in[6];  // (H,2H)
    float* out = (float*)d_out;                 // (B,T,H)

    float* pe = (float*)d_ws;                    // NB*NS*NH
    float* pq = pe + (size_t)NB * NS * NH;       // NB*NT*NH
    float* w  = pq + (size_t)NB * NT * NH;       // NH
    float* e  = w + NH;                          // NB*NT*NS
    float* c  = e + (size_t)NB * NT * NS;        // NB*NT*NH

    k1_proj<<<320, 512, 0, stream>>>(enc, q, Wh, Ws, v, pe, pq, w);
    k2_score<<<dim3(NS / 64, NT / 8, NB), 512, 0, stream>>>(pe, pq, w, e);
    k3_ctx<<<dim3(NH / 64, NT / 4, NB), 256, 0, stream>>>(e, enc, lens, c);
    k4_out<<<256, 512, 0, stream>>>(q, c, Wout, out);
}